// Round 12
// baseline (338.078 us; speedup 1.0000x reference)
//
#include <hip/hip_runtime.h>
#include <hip/hip_bf16.h>
#include <math.h>

// GAT 2-layer fused pipeline for MI355X (gfx950).
// Dims per reference: D_IN=D_H=128, D_OUT=64, SLOPE=0.2.
//
// Round-12 = round-11 with the W-staging bug fixed: the LDS staging loops
// copied only half of the packed hi|lo weight buffer (MODE 0/1: 8 iters for
// a 32768-short buffer; MODE 2: 4 iters for 16384-short weights), leaving
// the lo segments uninitialized -> NaN. Now 16 / 8 iterations respectively.
// Structure (from r11):
//  - GEMM: full-C blocks (128 rows x all C), whole W hi+lo (64 KB) in LDS;
//    L0 1 piece, L1 2 pieces (q/p), L2 fused dual; activations in one
//    interleaved Mpk[row][hi*128|lo*128] buffer; A prefetched all-upfront.
//  - CSR: atomic-free two-level counting sort (r10).
//  - gat_agg: scalar CSR walk, bf16 p gather, DPP reduce (r9/r10).

#define SLOPE 0.2f

typedef __attribute__((ext_vector_type(8))) __bf16 bf16x8;
typedef __attribute__((ext_vector_type(4))) float f32x4;

__device__ __forceinline__ float gelu_erf(float x) {
    return 0.5f * x * (1.0f + erff(x * 0.70710678118654752f));
}

__device__ __forceinline__ unsigned short f2bf(float f) {  // RNE
    unsigned int u = __float_as_uint(f);
    return (unsigned short)((u + 0x7fffu + ((u >> 16) & 1u)) >> 16);
}
__device__ __forceinline__ float bf2f(unsigned short h) {
    return __uint_as_float((unsigned int)h << 16);
}

// Full-wave (64-lane) f32 sum via DPP; result broadcast via readlane 63.
__device__ __forceinline__ float wave_sum_bcast(float x) {
    x += __int_as_float(__builtin_amdgcn_update_dpp(0, __float_as_int(x), 0x111, 0xF, 0xF, true));
    x += __int_as_float(__builtin_amdgcn_update_dpp(0, __float_as_int(x), 0x112, 0xF, 0xF, true));
    x += __int_as_float(__builtin_amdgcn_update_dpp(0, __float_as_int(x), 0x114, 0xF, 0xF, true));
    x += __int_as_float(__builtin_amdgcn_update_dpp(0, __float_as_int(x), 0x118, 0xF, 0xF, true));
    x += __int_as_float(__builtin_amdgcn_update_dpp(0, __float_as_int(x), 0x142, 0xF, 0xF, true));
    x += __int_as_float(__builtin_amdgcn_update_dpp(0, __float_as_int(x), 0x143, 0xF, 0xF, true));
    return __int_as_float(__builtin_amdgcn_readlane(__float_as_int(x), 63));
}

// ---------------- weight prepack ---------------------------------------------
// Pack index i = ((ct*4+ks)*64 + lane)*8 + j  ->  W[k][n],
// k = ks*32 + (lane>>4)*8 + j,  n = ct*16 + (lane&15).  hi at [i], lo at [CE+i].
__global__ __launch_bounds__(256) void pack_w(
    const float* __restrict__ W0,  const float* __restrict__ Wq1,
    const float* __restrict__ Wp1, const float* __restrict__ Wq2,
    const float* __restrict__ Wp2,
    unsigned short* __restrict__ P0,  unsigned short* __restrict__ Pq1,
    unsigned short* __restrict__ Pp1, unsigned short* __restrict__ Pq2,
    unsigned short* __restrict__ Pp2)
{
    const float* W; unsigned short* P; int C;
    switch (blockIdx.y) {
        case 0:  W = W0;  P = P0;  C = 128; break;
        case 1:  W = Wq1; P = Pq1; C = 128; break;
        case 2:  W = Wp1; P = Pp1; C = 128; break;
        case 3:  W = Wq2; P = Pq2; C = 64;  break;
        default: W = Wp2; P = Pp2; C = 64;  break;
    }
    int i = blockIdx.x * 256 + threadIdx.x;
    int CE = C * 128;
    if (i >= CE) return;
    int j = i & 7, l = (i >> 3) & 63, ks = (i >> 9) & 3, ct = i >> 11;
    int k = ks * 32 + ((l >> 4) << 3) + j;
    int n = ct * 16 + (l & 15);
    float v = W[k * C + n];
    unsigned short hb = f2bf(v);
    P[i] = hb;
    P[CE + i] = f2bf(v - bf2f(hb));
}

// ---------------- MFMA GEMM -------------------------------------------------
// block = 128 rows (4 waves x 2 row-frags) x all C cols; 64 KB W in LDS.
// MODE 0: A = x fp32 (convert in-kernel), out = Mpk (hi|lo interleaved rows).
// MODE 1: A = Mpk; blockIdx.y selects output: 0 -> q fp32 (W=P1), 1 -> p bf16 (W=P2).
// MODE 2: A = Mpk; fused dual C=64: q fp32 (P1) + p bf16 (P2).
template <int C, int MODE>
__global__ __launch_bounds__(256) void mfma_gemm(
    const float* __restrict__ Af, const unsigned short* __restrict__ Apk,
    const unsigned short* __restrict__ P1, const float* __restrict__ b1,
    const unsigned short* __restrict__ P2, const float* __restrict__ b2,
    float* __restrict__ outq, unsigned short* __restrict__ outp,
    unsigned short* __restrict__ oMpk, int N)
{
    constexpr int CT = C / 16;            // 8 or 4
    constexpr int CE = C * 128;
    constexpr int RF = 2;
    constexpr int NO = (MODE == 2) ? 2 : 1;

    __shared__ __align__(16) unsigned short Blds[32768];  // 64 KB

    const int t = threadIdx.x;
    const int lane = t & 63;
    const int w = t >> 6;
    const int row0 = blockIdx.x * 128 + w * 32;
    const int mcol = lane & 15;
    const int koff = (lane >> 4) * 8;

    int wsel = (MODE == 1) ? blockIdx.y : 0;

    // ---- stage W (FIXED iteration counts: full hi+lo staged) ----
    if (MODE == 2) {
        // P1 (hi|lo, 16384 shorts) -> Blds[0..16384); P2 -> Blds[16384..32768)
#pragma unroll
        for (int i = 0; i < 8; i++) {
            int idx = (t + i * 256) * 8;
            *reinterpret_cast<uint4*>(&Blds[idx])         = *reinterpret_cast<const uint4*>(&P1[idx]);
            *reinterpret_cast<uint4*>(&Blds[16384 + idx]) = *reinterpret_cast<const uint4*>(&P2[idx]);
        }
    } else {
        const unsigned short* Pw = (MODE == 1 && wsel) ? P2 : P1;
#pragma unroll
        for (int i = 0; i < 16; i++) {     // 2*CE = 32768 shorts for C=128
            int idx = (t + i * 256) * 8;
            *reinterpret_cast<uint4*>(&Blds[idx]) = *reinterpret_cast<const uint4*>(&Pw[idx]);
        }
    }

    f32x4 acc[NO][CT][RF];
#pragma unroll
    for (int o = 0; o < NO; o++)
#pragma unroll
        for (int c = 0; c < CT; c++)
#pragma unroll
            for (int r = 0; r < RF; r++) acc[o][c][r] = (f32x4){0.f, 0.f, 0.f, 0.f};

    bf16x8 ah[4][RF], al[4][RF];
    if (MODE != 0) {
        // prefetch ALL A fragments upfront: 16 dwordx4 in flight
#pragma unroll
        for (int ks = 0; ks < 4; ks++)
#pragma unroll
            for (int rf = 0; rf < RF; rf++) {
                int gr = row0 + rf * 16 + mcol;
                union { bf16x8 v; uint4 q; } H, L;
                H.q = make_uint4(0, 0, 0, 0); L.q = H.q;
                if (gr < N) {
                    const unsigned short* rp = Apk + (size_t)gr * 256 + ks * 32 + koff;
                    H.q = *reinterpret_cast<const uint4*>(rp);
                    L.q = *reinterpret_cast<const uint4*>(rp + 128);
                }
                ah[ks][rf] = H.v; al[ks][rf] = L.v;
            }
    } else {
        // fp32 -> hi/lo conversion, all upfront (16 x 2 float4 loads)
#pragma unroll
        for (int ks = 0; ks < 4; ks++)
#pragma unroll
            for (int rf = 0; rf < RF; rf++) {
                int gr = row0 + rf * 16 + mcol;
                float4 v0 = make_float4(0.f, 0.f, 0.f, 0.f), v1 = v0;
                if (gr < N) {
                    const float* ap = Af + (size_t)gr * 128 + ks * 32 + koff;
                    v0 = *reinterpret_cast<const float4*>(ap);
                    v1 = *reinterpret_cast<const float4*>(ap + 4);
                }
                union { bf16x8 v; unsigned short u[8]; } H, L;
                const float* f0 = reinterpret_cast<const float*>(&v0);
                const float* f1 = reinterpret_cast<const float*>(&v1);
#pragma unroll
                for (int j = 0; j < 4; j++) {
                    unsigned short hb = f2bf(f0[j]);
                    H.u[j] = hb; L.u[j] = f2bf(f0[j] - bf2f(hb));
                    unsigned short hb2 = f2bf(f1[j]);
                    H.u[4 + j] = hb2; L.u[4 + j] = f2bf(f1[j] - bf2f(hb2));
                }
                ah[ks][rf] = H.v; al[ks][rf] = L.v;
            }
    }
    __syncthreads();   // W staged

#pragma unroll
    for (int ks = 0; ks < 4; ks++) {
#pragma unroll
        for (int ct = 0; ct < CT; ct++) {
            int off = (ct * 4 + ks) * 512 + lane * 8;
#pragma unroll
            for (int o = 0; o < NO; o++) {
                const int base = (MODE == 2) ? o * 16384 : 0;
                const int ce   = (MODE == 2) ? 8192 : CE;
                bf16x8 bh = *reinterpret_cast<const bf16x8*>(&Blds[base + off]);
                bf16x8 bl = *reinterpret_cast<const bf16x8*>(&Blds[base + ce + off]);
#pragma unroll
                for (int rf = 0; rf < RF; rf++) {
                    acc[o][ct][rf] = __builtin_amdgcn_mfma_f32_16x16x32_bf16(ah[ks][rf], bh, acc[o][ct][rf], 0, 0, 0);
                    acc[o][ct][rf] = __builtin_amdgcn_mfma_f32_16x16x32_bf16(al[ks][rf], bh, acc[o][ct][rf], 0, 0, 0);
                    acc[o][ct][rf] = __builtin_amdgcn_mfma_f32_16x16x32_bf16(ah[ks][rf], bl, acc[o][ct][rf], 0, 0, 0);
                }
            }
        }
    }

    // ---- epilogue: C/D layout col=lane&15, row=(lane>>4)*4+reg ----
#pragma unroll
    for (int o = 0; o < NO; o++) {
        const float* bb = (MODE == 2) ? (o ? b2 : b1) : (wsel ? b2 : b1);
#pragma unroll
        for (int ct = 0; ct < CT; ct++) {
            int col = ct * 16 + mcol;
            float bv = bb[col];
#pragma unroll
            for (int rf = 0; rf < RF; rf++) {
#pragma unroll
                for (int r = 0; r < 4; r++) {
                    int gr = row0 + rf * 16 + (lane >> 4) * 4 + r;
                    if (gr >= N) continue;
                    float v = acc[o][ct][rf][r] + bv;
                    if (MODE == 0) {
                        v = gelu_erf(v);
                        unsigned short hb = f2bf(v);
                        oMpk[(size_t)gr * 256 + col] = hb;
                        oMpk[(size_t)gr * 256 + 128 + col] = f2bf(v - bf2f(hb));
                    } else if (MODE == 1) {
                        if (wsel == 0) outq[(size_t)gr * C + col] = v;
                        else           outp[(size_t)gr * C + col] = f2bf(v);
                    } else {
                        if (o == 0) outq[(size_t)gr * C + col] = v;
                        else        outp[(size_t)gr * C + col] = f2bf(v);
                    }
                }
            }
        }
    }
}

// ---------------- CSR build: atomic-free two-level counting sort -------------
__global__ __launch_bounds__(256) void hist_coarse(
    const int* __restrict__ dst, int* __restrict__ gh, int E, int CB)
{
    __shared__ int cnt[4096];
    const int blk = blockIdx.x;     // 0..63
    const int t = threadIdx.x;
    for (int b = t; b < CB; b += 256) cnt[b] = 0;
    __syncthreads();
    const int epb = (E + 63) / 64;
    const int s = blk * epb;
    const int e_ = (s + epb < E) ? s + epb : E;
    for (int i = s + t; i < e_; i += 256)
        atomicAdd(&cnt[dst[i] >> 4], 1);
    __syncthreads();
    for (int b = t; b < CB; b += 256)
        gh[b * 64 + blk] = cnt[b];
}

__global__ __launch_bounds__(256) void scan1_kernel(const int* __restrict__ gh,
                                                    int* __restrict__ gscan,
                                                    int* __restrict__ bsum, int M)
{
    __shared__ int lds[256];
    int t = threadIdx.x;
    int i = blockIdx.x * 256 + t;
    int v = (i < M) ? gh[i] : 0;
    lds[t] = v;
    __syncthreads();
    int x = v;
    for (int off = 1; off < 256; off <<= 1) {
        int y = (t >= off) ? lds[t - off] : 0;
        __syncthreads();
        x += y;
        lds[t] = x;
        __syncthreads();
    }
    if (i < M) gscan[i] = x - v;
    if (t == 255) bsum[blockIdx.x] = x;
}

__global__ __launch_bounds__(1024) void scan2_kernel(int* __restrict__ bsum, int NB)
{
    __shared__ int lds[1024];
    int t = threadIdx.x;
    int v = (t < NB) ? bsum[t] : 0;
    lds[t] = v;
    __syncthreads();
    int x = v;
    for (int off = 1; off < 1024; off <<= 1) {
        int y = (t >= off) ? lds[t - off] : 0;
        __syncthreads();
        x += y;
        lds[t] = x;
        __syncthreads();
    }
    if (t < NB) bsum[t] = x - v;
}

__global__ __launch_bounds__(256) void scan3_kernel(int* __restrict__ gscan,
                                                    const int* __restrict__ bsum, int M)
{
    int i = blockIdx.x * 256 + threadIdx.x;
    if (i < M) gscan[i] += bsum[blockIdx.x];
}

__global__ __launch_bounds__(256) void scatter_coarse(
    const int* __restrict__ src, const int* __restrict__ dst,
    const int* __restrict__ gscan, int2* __restrict__ pairs, int E, int CB)
{
    __shared__ int cur[4096];
    const int blk = blockIdx.x;     // 0..63
    const int t = threadIdx.x;
    for (int b = t; b < CB; b += 256)
        cur[b] = gscan[b * 64 + blk];
    __syncthreads();
    const int epb = (E + 63) / 64;
    const int s = blk * epb;
    const int e_ = (s + epb < E) ? s + epb : E;
    for (int i = s + t; i < e_; i += 256) {
        int d = dst[i];
        int sv = src[i];
        int pos = atomicAdd(&cur[d >> 4], 1);   // LDS atomic
        pairs[pos] = make_int2(d, sv);
    }
}

__global__ __launch_bounds__(256) void finalize_kernel(
    const int2* __restrict__ pairs, const int* __restrict__ gscan,
    int* __restrict__ offs, int* __restrict__ csr_src, int N, int E, int CB)
{
    const int c = blockIdx.x;
    const int t = threadIdx.x;
    __shared__ unsigned int cnt[8], rnk[8];
    __shared__ int pref[16];
    if (t < 8) { cnt[t] = 0u; rnk[t] = 0u; }
    __syncthreads();

    const int s  = gscan[c * 64];
    const int e_ = (c + 1 < CB) ? gscan[(c + 1) * 64] : E;
    const int base = c * 16;

    for (int i = s + t; i < e_; i += 256) {
        int d = pairs[i].x - base;    // 0..15
        atomicAdd(&cnt[d >> 1], 1u << ((d & 1) * 16));
    }
    __syncthreads();
    if (t == 0) {
        int run = s;
        for (int j = 0; j < 16; j++) {
            pref[j] = run;
            run += (int)((cnt[j >> 1] >> ((j & 1) * 16)) & 0xffffu);
        }
    }
    __syncthreads();
    if (t < 16 && base + t < N) offs[base + t] = pref[t];
    if (c == CB - 1 && t == 0) offs[N] = E;

    for (int i = s + t; i < e_; i += 256) {
        int2 pr = pairs[i];
        int d = pr.x - base;
        unsigned int old = atomicAdd(&rnk[d >> 1], 1u << ((d & 1) * 16));
        int r = (int)((old >> ((d & 1) * 16)) & 0xffffu);
        csr_src[pref[d] + r] = pr.y;
    }
}

// ---------------- fused GAT edge-softmax + aggregation -----------------------
// One wave per dst node (wave-uniform via readfirstlane -> scalar CSR walk).
// p is bf16: D=128 -> packed dword per lane; D=64 -> ushort per lane.
// EPI 0 (D=128): m2 = gelu(h+bvec) -> Mpk row (hi uint at node*128+lane,
//                lo uint at node*128+64+lane).   EPI 1 (D=64): fp32 out.
template <int D, int EPI>
__global__ __launch_bounds__(256) void gat_agg(
    const float* __restrict__ q, const void* __restrict__ pv_,
    const float* __restrict__ a, const float* __restrict__ bvec,
    const int* __restrict__ offs, const int* __restrict__ csr_src,
    float* __restrict__ out, unsigned int* __restrict__ mpk, int N)
{
    constexpr int VPL = D / 64;  // 2 (D=128) or 1 (D=64)
    const int lane = threadIdx.x & 63;
    const int node = __builtin_amdgcn_readfirstlane(blockIdx.x * 4 + (threadIdx.x >> 6));
    if (node >= N) return;  // scalar branch

    const unsigned int* pp32 = (const unsigned int*)pv_;
    const unsigned short* pp16 = (const unsigned short*)pv_;

    float qv[VPL], av[VPL], acc[VPL];
#pragma unroll
    for (int v = 0; v < VPL; v++) {
        qv[v] = q[(size_t)node * D + lane * VPL + v];
        av[v] = a[lane * VPL + v];
        acc[v] = 0.f;
    }
    float denom = 0.f;

    const int e0 = offs[node], e1 = offs[node + 1];
    int e = e0;

    for (; e + 4 <= e1; e += 4) {
        int s0 = csr_src[e + 0];
        int s1 = csr_src[e + 1];
        int s2 = csr_src[e + 2];
        int s3 = csr_src[e + 3];
        float pv0[VPL], pv1[VPL], pv2[VPL], pv3[VPL];
        if (VPL == 2) {
            unsigned int u0 = pp32[(size_t)s0 * 64 + lane];
            unsigned int u1 = pp32[(size_t)s1 * 64 + lane];
            unsigned int u2 = pp32[(size_t)s2 * 64 + lane];
            unsigned int u3 = pp32[(size_t)s3 * 64 + lane];
            pv0[0] = __uint_as_float(u0 << 16); pv0[1] = __uint_as_float(u0 & 0xffff0000u);
            pv1[0] = __uint_as_float(u1 << 16); pv1[1] = __uint_as_float(u1 & 0xffff0000u);
            pv2[0] = __uint_as_float(u2 << 16); pv2[1] = __uint_as_float(u2 & 0xffff0000u);
            pv3[0] = __uint_as_float(u3 << 16); pv3[1] = __uint_as_float(u3 & 0xffff0000u);
        } else {
            pv0[0] = bf2f(pp16[(size_t)s0 * 64 + lane]);
            pv1[0] = bf2f(pp16[(size_t)s1 * 64 + lane]);
            pv2[0] = bf2f(pp16[(size_t)s2 * 64 + lane]);
            pv3[0] = bf2f(pp16[(size_t)s3 * 64 + lane]);
        }
        float pa0 = 0.f, pa1 = 0.f, pa2 = 0.f, pa3 = 0.f;
#pragma unroll
        for (int v = 0; v < VPL; v++) {
            float t0 = qv[v] + pv0[v];
            float t1 = qv[v] + pv1[v];
            float t2 = qv[v] + pv2[v];
            float t3 = qv[v] + pv3[v];
            t0 = fmaxf(t0, SLOPE * t0);
            t1 = fmaxf(t1, SLOPE * t1);
            t2 = fmaxf(t2, SLOPE * t2);
            t3 = fmaxf(t3, SLOPE * t3);
            pa0 = fmaf(t0, av[v], pa0);
            pa1 = fmaf(t1, av[v], pa1);
            pa2 = fmaf(t2, av[v], pa2);
            pa3 = fmaf(t3, av[v], pa3);
        }
        float w0 = wave_sum_bcast(pa0);
        float w1 = wave_sum_bcast(pa1);
        float w2 = wave_sum_bcast(pa2);
        float w3 = wave_sum_bcast(pa3);
        float es0 = __expf(w0);
        float es1 = __expf(w1);
        float es2 = __expf(w2);
        float es3 = __expf(w3);
        denom += (es0 + es1) + (es2 + es3);
#pragma unroll
        for (int v = 0; v < VPL; v++) {
            acc[v] = fmaf(es0, pv0[v], acc[v]);
            acc[v] = fmaf(es1, pv1[v], acc[v]);
            acc[v] = fmaf(es2, pv2[v], acc[v]);
            acc[v] = fmaf(es3, pv3[v], acc[v]);
        }
    }
    for (; e < e1; e++) {
        int s0 = csr_src[e];
        float pv0[VPL];
        if (VPL == 2) {
            unsigned int u0 = pp32[(size_t)s0 * 64 + lane];
            pv0[0] = __uint_as_float(u0 << 16);
            pv0[1] = __uint_as_float(u0 & 0xffff0000u);
        } else {
            pv0[0] = bf2f(pp16[(size_t)s0 * 64 + lane]);
        }
        float pa0 = 0.f;
#pragma unroll
        for (int v = 0; v < VPL; v++) {
            float t0 = qv[v] + pv0[v];
            t0 = fmaxf(t0, SLOPE * t0);
            pa0 = fmaf(t0, av[v], pa0);
        }
        float es0 = __expf(wave_sum_bcast(pa0));
        denom += es0;
#pragma unroll
        for (int v = 0; v < VPL; v++)
            acc[v] = fmaf(es0, pv0[v], acc[v]);
    }

    float inv = (denom != 0.f) ? 1.f / denom : 0.f;  // zero-degree -> agg = 0
    if (EPI == 0) {
        float g0 = gelu_erf(acc[0] * inv + bvec[lane * 2 + 0]);
        float g1 = gelu_erf(acc[1] * inv + bvec[lane * 2 + 1]);
        unsigned short h0 = f2bf(g0), h1 = f2bf(g1);
        unsigned short l0 = f2bf(g0 - bf2f(h0)), l1 = f2bf(g1 - bf2f(h1));
        mpk[(size_t)node * 128 + lane]      = (unsigned int)h0 | ((unsigned int)h1 << 16);
        mpk[(size_t)node * 128 + 64 + lane] = (unsigned int)l0 | ((unsigned int)l1 << 16);
    } else {
        out[(size_t)node * D + lane] = acc[0] * inv + bvec[lane];
    }
}

// ---------------- launch ------------------------------------------------------
extern "C" void kernel_launch(void* const* d_in, const int* in_sizes, int n_in,
                              void* d_out, int out_size, void* d_ws, size_t ws_size,
                              hipStream_t stream)
{
    const float* x     = (const float*)d_in[0];
    const float* W0    = (const float*)d_in[1];
    const float* b0    = (const float*)d_in[2];
    const float* Wq1   = (const float*)d_in[3];
    const float* bq1   = (const float*)d_in[4];
    const float* Wp1   = (const float*)d_in[5];
    const float* bp1   = (const float*)d_in[6];
    const float* a1    = (const float*)d_in[7];
    const float* bg2   = (const float*)d_in[8];
    const float* Wq2   = (const float*)d_in[9];
    const float* bq2   = (const float*)d_in[10];
    const float* Wp2   = (const float*)d_in[11];
    const float* bp2   = (const float*)d_in[12];
    const float* a2    = (const float*)d_in[13];
    const float* b_out = (const float*)d_in[14];
    const int*   src   = (const int*)d_in[15];
    const int*   dst   = (const int*)d_in[16];

    const int N = in_sizes[0] / 128;
    const int E = in_sizes[15];
    float* out = (float*)d_out;

    // workspace carve
    float* q_buf        = (float*)d_ws;                      // N*128 f32
    unsigned short* pb  = (unsigned short*)(q_buf + (size_t)N * 128);  // N*128 bf16
    unsigned short* Mpk = pb + (size_t)N * 128;              // N*256 (hi|lo rows)
    unsigned short* P0  = Mpk + (size_t)N * 256;
    unsigned short* Pq1 = P0  + 128 * 128 * 2;
    unsigned short* Pp1 = Pq1 + 128 * 128 * 2;
    unsigned short* Pq2 = Pp1 + 128 * 128 * 2;
    unsigned short* Pp2 = Pq2 + 128 * 64 * 2;
    int* offs    = (int*)(Pp2 + 128 * 64 * 2);
    int* csr_src = offs + (N + 2);
    const int CB = (N + 15) / 16;          // coarse bins (<= 4096 for N<=65536)
    const int M  = CB * 64;
    int* gh    = csr_src + E;
    int* gscan = gh + M;
    int* bsum  = gscan + M;                // 1024 ints
    int2* pairs = (int2*)q_buf;            // aliases q_buf (dead until gemm L1)

    const int NB1 = (M + 255) / 256;       // <= 1024

    // 1) weight prepack
    pack_w<<<dim3(64, 5), 256, 0, stream>>>(W0, Wq1, Wp1, Wq2, Wp2,
                                            P0, Pq1, Pp1, Pq2, Pp2);
    // 2-7) CSR build (atomic-free two-level counting sort)
    hist_coarse<<<64, 256, 0, stream>>>(dst, gh, E, CB);
    scan1_kernel<<<NB1, 256, 0, stream>>>(gh, gscan, bsum, M);
    scan2_kernel<<<1, 1024, 0, stream>>>(bsum, NB1);
    scan3_kernel<<<NB1, 256, 0, stream>>>(gscan, bsum, M);
    scatter_coarse<<<64, 256, 0, stream>>>(src, dst, gscan, pairs, E, CB);
    finalize_kernel<<<CB, 256, 0, stream>>>(pairs, gscan, offs, csr_src, N, E, CB);

    const int GB = (N + 127) / 128;

    // 8) layer 0: m1 = gelu(x@W0 + b0) -> Mpk
    mfma_gemm<128, 0><<<GB, 256, 0, stream>>>(
        x, nullptr, P0, b0, nullptr, nullptr,
        nullptr, nullptr, Mpk, N);
    // 9) layer 1 projections: piece 0 -> q1 fp32 (Pq1), piece 1 -> p1 bf16 (Pp1)
    mfma_gemm<128, 1><<<dim3(GB, 2), 256, 0, stream>>>(
        nullptr, Mpk, Pq1, bq1, Pp1, bp1,
        q_buf, pb, nullptr, N);
    // 10) layer 1 GAT -> m2 = gelu(h1 + bg2) -> Mpk
    gat_agg<128, 0><<<(N + 3) / 4, 256, 0, stream>>>(
        q_buf, pb, a1, bg2, offs, csr_src,
        nullptr, (unsigned int*)Mpk, N);
    // 11) layer 2 projections (fused dual): q2 fp32 + p2 bf16
    mfma_gemm<64, 2><<<GB, 256, 0, stream>>>(
        nullptr, Mpk, Pq2, bq2, Pp2, bp2,
        q_buf, pb, nullptr, N);
    // 12) layer 2 GAT + b_out -> d_out
    gat_agg<64, 1><<<(N + 3) / 4, 256, 0, stream>>>(
        q_buf, pb, a2, b_out, offs, csr_src,
        out, nullptr, N);
}